// Round 13
// baseline (124155.017 us; speedup 1.0000x reference)
//
#include <hip/hip_runtime.h>
#include <hip/hip_cooperative_groups.h>
#include <stdint.h>

namespace cg = cooperative_groups;

#ifndef THREEFRY_PARTITIONABLE
#define THREEFRY_PARTITIONABLE 1
#endif

#define LSEQ 128
#define BSZ  256
#define HD   512
#define G4   2048   // 4*HD

#define SEL_OFF  ((size_t)LSEQ * BSZ * LSEQ)            // 4194304
#define HY_OFF   (SEL_OFF + (size_t)LSEQ * BSZ)         // 4227072
#define CY_OFF   (HY_OFF + (size_t)BSZ * HD)            // 4358144

// ---------------- Threefry-2x32 (bit-exact vs JAX) ----------------
__device__ __forceinline__ uint32_t rotl_(uint32_t v, int r) { return (v << r) | (v >> (32 - r)); }

__device__ __forceinline__ void tf2x32(uint32_t k0, uint32_t k1,
                                       uint32_t x0, uint32_t x1,
                                       uint32_t &o0, uint32_t &o1)
{
  uint32_t k2 = k0 ^ k1 ^ 0x1BD11BDAu;
  x0 += k0; x1 += k1;
#define TFR(r) { x0 += x1; x1 = rotl_(x1,(r)); x1 ^= x0; }
  TFR(13) TFR(15) TFR(26) TFR(6)
  x0 += k1; x1 += k2 + 1u;
  TFR(17) TFR(29) TFR(16) TFR(24)
  x0 += k2; x1 += k0 + 2u;
  TFR(13) TFR(15) TFR(26) TFR(6)
  x0 += k0; x1 += k1 + 3u;
  TFR(17) TFR(29) TFR(16) TFR(24)
  x0 += k1; x1 += k2 + 4u;
  TFR(13) TFR(15) TFR(26) TFR(6)
  x0 += k2; x1 += k0 + 5u;
#undef TFR
  o0 = x0; o1 = x1;
}

__device__ __forceinline__ void step_key(int t, uint32_t &kA, uint32_t &kB)
{
#if THREEFRY_PARTITIONABLE
  uint32_t o0, o1;
  tf2x32(0u, 1u, 0u, (uint32_t)t, o0, o1);
  kA = o0; kB = o1;
#else
  uint32_t o0, o1;
  uint32_t j = 2u * (uint32_t)t;
  if (j < 127u) { tf2x32(0u, 1u, j, 127u + j, o0, o1); kA = o0; }
  else          { tf2x32(0u, 1u, j - 127u, j, o0, o1); kA = o1; }
  j = 2u * (uint32_t)t + 1u;
  if (j < 127u) { tf2x32(0u, 1u, j, 127u + j, o0, o1); kB = o0; }
  else          { tf2x32(0u, 1u, j - 127u, j, o0, o1); kB = o1; }
#endif
}

__device__ __forceinline__ uint32_t draw_bits(uint32_t kA, uint32_t kB, uint32_t n)
{
  uint32_t y0, y1;
#if THREEFRY_PARTITIONABLE
  tf2x32(kA, kB, 0u, n, y0, y1);
  return y0 ^ y1;
#else
  uint32_t i0 = (n < 16384u) ? n : n - 16384u;
  tf2x32(kA, kB, i0, i0 + 16384u, y0, y1);
  return (n < 16384u) ? y0 : y1;
#endif
}

// ---------------- fast f32 tanh (branch-free, ~1e-7 abs) ----------------
__device__ __forceinline__ float tanh_f(float xf)
{
  float ax = fabsf(xf);
  float z  = fminf(ax * 2.8853900817779268f, 50.0f);  // 2*log2(e), clamp
  float e  = __builtin_amdgcn_exp2f(z);
  float d  = e + 1.0f;
  float r0 = __builtin_amdgcn_rcpf(d);
  float r  = fmaf(fmaf(-d, r0, 1.0f), r0, r0);        // Newton: r ~= 1/d
  return copysignf(fmaf(-2.0f, r, 1.0f), xf);         // tanh(|x|) = 1 - 2/(e+1)
}

// ---------------- f32-input GEMM, chunked-f64 accumulate (R11 version) ----------------
// Used only for the one-time e_g/e_p precompute (out_mode 3).
template<int CHUNK>
__global__ __launch_bounds__(512)
void gemm32(const float* __restrict__ A0, int lda,
            const float* __restrict__ B0, int ldb,
            const float* __restrict__ bias,
            float* __restrict__ Cf0, int N, int K, int out_mode)
{
  constexpr int BK = 32;
  __shared__ float As[BK][64];
  __shared__ float Bs[BK][64];
  const int tid = threadIdx.x;
  const int tx = tid & 31, ty = tid >> 5;
  const float* A = A0;
  const float* B = B0;
  const int m0 = blockIdx.x * 64;
  const int n0 = blockIdx.y * 64;
  const int r_ = tid >> 3, kq = (tid & 7) * 4;

  double acc[4][2];
  float  c32[4][2];
#pragma unroll
  for (int i = 0; i < 4; ++i)
#pragma unroll
    for (int j = 0; j < 2; ++j) { acc[i][j] = 0.0; c32[i][j] = 0.0f; }

  float4 w0 = *(const float4*)(B + (size_t)(n0 + r_) * ldb + kq);
  float4 u0 = *(const float4*)(A + (size_t)(m0 + r_) * lda + kq);

  for (int k0 = 0; k0 < K; k0 += BK) {
    __syncthreads();
    Bs[kq + 0][r_] = w0.x; Bs[kq + 1][r_] = w0.y;
    Bs[kq + 2][r_] = w0.z; Bs[kq + 3][r_] = w0.w;
    As[kq + 0][r_] = u0.x; As[kq + 1][r_] = u0.y;
    As[kq + 2][r_] = u0.z; As[kq + 3][r_] = u0.w;
    __syncthreads();

    float4 nw0 = w0, nu0 = u0;
    if (k0 + BK < K) {
      nw0 = *(const float4*)(B + (size_t)(n0 + r_) * ldb + (k0 + BK) + kq);
      nu0 = *(const float4*)(A + (size_t)(m0 + r_) * lda + (k0 + BK) + kq);
    }

#pragma unroll
    for (int kk = 0; kk < BK; ++kk) {
      float4 av = *(const float4*)&As[kk][4 * ty];
      float2 bv = *(const float2*)&Bs[kk][2 * tx];
      float a[4] = { av.x, av.y, av.z, av.w };
#pragma unroll
      for (int i = 0; i < 4; ++i) {
        c32[i][0] = fmaf(a[i], bv.x, c32[i][0]);
        c32[i][1] = fmaf(a[i], bv.y, c32[i][1]);
      }
      if ((kk & (CHUNK - 1)) == (CHUNK - 1)) {
#pragma unroll
        for (int i = 0; i < 4; ++i)
#pragma unroll
          for (int j = 0; j < 2; ++j) { acc[i][j] += (double)c32[i][j]; c32[i][j] = 0.0f; }
      }
    }
    w0 = nw0; u0 = nu0;
  }

#pragma unroll
  for (int i = 0; i < 4; ++i) {
    int m = m0 + 4 * ty + i;
#pragma unroll
    for (int j = 0; j < 2; ++j) {
      int n = n0 + 2 * tx + j;
      double v = acc[i][j] + (bias ? (double)bias[n] : 0.0);
      if (out_mode == 3) {
        Cf0[(((size_t)(m & 255)) * HD + n) * LSEQ + (m >> 8)] = (float)v;
      } else {
        Cf0[(size_t)m * N + n] = (float)v;
      }
    }
  }
}

// ---------------- 512x512 transpose ----------------
__global__ __launch_bounds__(256)
void transpose512(const float* __restrict__ W, float* __restrict__ WT)
{
  __shared__ float tile[32][33];
  int bx = blockIdx.x * 32, by = blockIdx.y * 32;
  int x = threadIdx.x & 31, y = threadIdx.x >> 5;   // 32 x 8
#pragma unroll
  for (int j = 0; j < 32; j += 8)
    tile[y + j][x] = W[(size_t)(by + y + j) * HD + bx + x];
  __syncthreads();
#pragma unroll
  for (int j = 0; j < 32; j += 8)
    WT[(size_t)(bx + y + j) * HD + by + x] = tile[x][y + j];
}

// score-phase per-element compute: pure-f32 tanh, f64 accumulate (R11)
#define SCOMP(A0_, A1_, A2_, A3_, V4, IT)                         \
  {                                                               \
    const int h_ = (IT) * 16 + hh;                                \
    const float  xq_ = (float)qs[h_];                             \
    const double vv_ = (double)vs[h_];                            \
    A0_ += vv_ * (double)tanh_f(xq_ + (V4).x);                    \
    A1_ += vv_ * (double)tanh_f(xq_ + (V4).y);                    \
    A2_ += vv_ * (double)tanh_f(xq_ + (V4).z);                    \
    A3_ += vv_ * (double)tanh_f(xq_ + (V4).w);                    \
  }

// ---------------- persistent cooperative kernel: all 127 steps ----------------
struct DecParams {
  const float *Wi, *Wh, *bi, *bh;
  const float *WqT, *gbq, *pWqT, *pbq;
  const float *e_g, *e_p, *gv, *pv;
  const float *emb;
  float *g0f, *g1f;
  float *hf0, *hf1;
  double *cb0, *cb1;
  float *decb;
  unsigned char *mask;
  float *out;
};

__global__ __launch_bounds__(512)
void persistent_kernel(DecParams p)
{
  cg::grid_group gridg = cg::this_grid();
  const int tid = threadIdx.x;
  const int bid = blockIdx.x;

  // shared (phase A + phase B; ~45 KB, 1 block/CU)
  __shared__ float  As[32][64];
  __shared__ float  Bsh[32][64];
  __shared__ float  hs[HD];
  __shared__ double qs[HD];
  __shared__ float  vs[HD];
  __shared__ double part[16][LSEQ];
  __shared__ double gls[HD];
  __shared__ double sarr[LSEQ];
  __shared__ double red[4];
  __shared__ double wv[2];
  __shared__ int    wi[2];
  __shared__ int    selidx;

  // phase-A block mapping: bid -> (mb, nb, z), 4 x 32 x 2 = 256
  const int zA  = bid & 1;
  const int nbA = (bid >> 1) & 31;
  const int mbA = bid >> 6;
  const int m0 = mbA * 64, n0 = nbA * 64;
  const float* Bw = zA ? p.Wh : p.Wi;
  float* Cg = zA ? p.g1f : p.g0f;
  const int r_ = tid >> 3, kq = (tid & 7) * 4;
  const int txA = tid & 31, tyA = tid >> 5;

  // phase-B indices
  const int b  = bid;
  const int l  = tid & 127;
  const int lg = tid & 31;
  const int hh = tid >> 5;
  const float* egbase = p.e_g + (size_t)b * (HD * LSEQ) + hh * LSEQ + lg * 4;
  const float* epbase = p.e_p + (size_t)b * (HD * LSEQ) + hh * LSEQ + lg * 4;

  for (int t = 0; t < LSEQ - 1; ++t) {
    const float*  hcur = (t & 1) ? p.hf1 : p.hf0;
    float*        hnxt = (t & 1) ? p.hf0 : p.hf1;
    const double* ccur = (t & 1) ? p.cb1 : p.cb0;
    double*       cnxt = (t & 1) ? p.cb0 : p.cb1;

    // ============ phase A: gates partial GEMM (R11 body, f32 out) ============
    {
      const float* A = zA ? hcur : p.decb;
      double acc[4][2];
      float  c32[4][2];
#pragma unroll
      for (int i = 0; i < 4; ++i)
#pragma unroll
        for (int j = 0; j < 2; ++j) { acc[i][j] = 0.0; c32[i][j] = 0.0f; }

      float4 w0 = *(const float4*)(Bw + (size_t)(n0 + r_) * HD + kq);
      float4 u0 = *(const float4*)(A + (size_t)(m0 + r_) * HD + kq);

      for (int k0 = 0; k0 < HD; k0 += 32) {
        __syncthreads();
        Bsh[kq + 0][r_] = w0.x; Bsh[kq + 1][r_] = w0.y;
        Bsh[kq + 2][r_] = w0.z; Bsh[kq + 3][r_] = w0.w;
        As[kq + 0][r_] = u0.x; As[kq + 1][r_] = u0.y;
        As[kq + 2][r_] = u0.z; As[kq + 3][r_] = u0.w;
        __syncthreads();

        float4 nw0 = w0, nu0 = u0;
        if (k0 + 32 < HD) {
          nw0 = *(const float4*)(Bw + (size_t)(n0 + r_) * HD + (k0 + 32) + kq);
          nu0 = *(const float4*)(A + (size_t)(m0 + r_) * HD + (k0 + 32) + kq);
        }

#pragma unroll
        for (int kk = 0; kk < 32; ++kk) {
          float4 av = *(const float4*)&As[kk][4 * tyA];
          float2 bv = *(const float2*)&Bsh[kk][2 * txA];
          float a[4] = { av.x, av.y, av.z, av.w };
#pragma unroll
          for (int i = 0; i < 4; ++i) {
            c32[i][0] = fmaf(a[i], bv.x, c32[i][0]);
            c32[i][1] = fmaf(a[i], bv.y, c32[i][1]);
          }
          if ((kk & 7) == 7) {
#pragma unroll
            for (int i = 0; i < 4; ++i)
#pragma unroll
              for (int j = 0; j < 2; ++j) { acc[i][j] += (double)c32[i][j]; c32[i][j] = 0.0f; }
          }
        }
        w0 = nw0; u0 = nu0;
      }

#pragma unroll
      for (int i = 0; i < 4; ++i) {
        int m = m0 + 4 * tyA + i;
#pragma unroll
        for (int j = 0; j < 2; ++j) {
          int n = n0 + 2 * txA + j;
          Cg[(size_t)m * G4 + n] = (float)acc[i][j];
        }
      }
    }
    __threadfence();
    gridg.sync();

    // ============ phase B: step (R11 step_fused body, verbatim) ============
    // early prefetch: glimpse batch 0 (latency hides under LSTM)
    float4 B0[8], B1[8];
#pragma unroll
    for (int j = 0; j < 8; ++j)
      B0[j] = *(const float4*)(egbase + (size_t)j * (16 * LSEQ));

    // ---- LSTM pointwise, u = tid ----
    {
      const int u = tid;
      const size_t base = (size_t)b * G4;
      double gi = (double)p.g0f[base + u]        + (double)p.g1f[base + u]        + (double)p.bi[u]        + (double)p.bh[u];
      double gf = (double)p.g0f[base + u + 512]  + (double)p.g1f[base + u + 512]  + (double)p.bi[u + 512]  + (double)p.bh[u + 512];
      double gg = (double)p.g0f[base + u + 1024] + (double)p.g1f[base + u + 1024] + (double)p.bi[u + 1024] + (double)p.bh[u + 1024];
      double go = (double)p.g0f[base + u + 1536] + (double)p.g1f[base + u + 1536] + (double)p.bi[u + 1536] + (double)p.bh[u + 1536];
      double si = 1.0 / (1.0 + exp(-gi));
      double sf = 1.0 / (1.0 + exp(-gf));
      double so = 1.0 / (1.0 + exp(-go));
      double cy = sf * ccur[(size_t)b * HD + u] + si * tanh(gg);
      double hy = so * tanh(cy);
      cnxt[(size_t)b * HD + u] = cy;
      float hyf = (float)hy;
      hnxt[(size_t)b * HD + u] = hyf;
      hs[u] = hyf;
    }
    __syncthreads();

    // ---- q1[h] = sum_k hs[k]*WqT[k][h], chunks of 8 -> f64, 32-deep batching ----
    {
      const int h = tid;
      const float* wcol = p.WqT + h;
      float wA[32], wB[32];
      double a = 0.0;
#pragma unroll
      for (int j = 0; j < 32; ++j) wA[j] = wcol[(size_t)j * HD];
#pragma unroll
      for (int pair = 0; pair < 8; ++pair) {
        const int kA = pair * 64;
#pragma unroll
        for (int j = 0; j < 32; ++j) wB[j] = wcol[(size_t)(kA + 32 + j) * HD];
#pragma unroll
        for (int c = 0; c < 4; ++c) {
          float c32 = 0.0f;
#pragma unroll
          for (int j = 0; j < 8; ++j)
            c32 = fmaf(hs[kA + c * 8 + j], wA[c * 8 + j], c32);
          a += (double)c32;
        }
        if (pair < 7) {
#pragma unroll
          for (int j = 0; j < 32; ++j) wA[j] = wcol[(size_t)(kA + 64 + j) * HD];
        }
#pragma unroll
        for (int c = 0; c < 4; ++c) {
          float c32 = 0.0f;
#pragma unroll
          for (int j = 0; j < 8; ++j)
            c32 = fmaf(hs[kA + 32 + c * 8 + j], wB[c * 8 + j], c32);
          a += (double)c32;
        }
      }
      qs[tid] = a + (double)p.gbq[tid];
      vs[tid] = p.gv[tid];
    }
    __syncthreads();

    // ---- glimpse scores: ping-pong 8-batches ----
    {
      double a0 = 0, a1 = 0, a2 = 0, a3 = 0;
#pragma unroll
      for (int j = 0; j < 8; ++j)
        B1[j] = *(const float4*)(egbase + (size_t)(8 + j) * (16 * LSEQ));
#pragma unroll
      for (int j = 0; j < 8; ++j) SCOMP(a0, a1, a2, a3, B0[j], j);
#pragma unroll
      for (int j = 0; j < 8; ++j)
        B0[j] = *(const float4*)(egbase + (size_t)(16 + j) * (16 * LSEQ));
#pragma unroll
      for (int j = 0; j < 8; ++j) SCOMP(a0, a1, a2, a3, B1[j], 8 + j);
#pragma unroll
      for (int j = 0; j < 8; ++j)
        B1[j] = *(const float4*)(egbase + (size_t)(24 + j) * (16 * LSEQ));
#pragma unroll
      for (int j = 0; j < 8; ++j) SCOMP(a0, a1, a2, a3, B0[j], 16 + j);
#pragma unroll
      for (int j = 0; j < 8; ++j) SCOMP(a0, a1, a2, a3, B1[j], 24 + j);
      part[hh][lg * 4 + 0] = a0;
      part[hh][lg * 4 + 1] = a1;
      part[hh][lg * 4 + 2] = a2;
      part[hh][lg * 4 + 3] = a3;
    }
    __syncthreads();

    bool   msk = false;
    double u = 0.0, pe = 0.0;
    if (tid < 128) {
      msk = p.mask[(size_t)b * LSEQ + l] != 0;
      u = 0.0;
#pragma unroll
      for (int o = 0; o < 16; ++o) u += part[o][l];
      if (msk) u = -__builtin_inf();
      double mx = u;
      for (int off = 32; off; off >>= 1) mx = fmax(mx, __shfl_xor(mx, off));
      if ((tid & 63) == 0) red[tid >> 6] = mx;
    }
    __syncthreads();
    if (tid < 128) {
      double mx = fmax(red[0], red[1]);
      pe = msk ? 0.0 : exp(u - mx);
      double sm = pe;
      for (int off = 32; off; off >>= 1) sm += __shfl_xor(sm, off);
      if ((tid & 63) == 0) red[2 + (tid >> 6)] = sm;
    }
    __syncthreads();
    if (tid < 128) sarr[l] = pe / (red[2] + red[3]);
    __syncthreads();

    // ---- g_l[h] = sum_l e_g[b][h][l]*s[l]  (contiguous rows, f64 acc) ----
    {
      // prefetch pointer batch 0 (latency hides under g_l + q2)
#pragma unroll
      for (int j = 0; j < 8; ++j)
        B0[j] = *(const float4*)(epbase + (size_t)j * (16 * LSEQ));

      const float4* row = (const float4*)(p.e_g + ((size_t)b * HD + tid) * LSEQ);
      float4 rA[4], rB[4];
      double a = 0.0;
#pragma unroll
      for (int j = 0; j < 4; ++j) rA[j] = row[j];
#pragma unroll
      for (int r = 0; r < 4; ++r) {
#pragma unroll
        for (int j = 0; j < 4; ++j) rB[j] = row[r * 8 + 4 + j];
#pragma unroll
        for (int j = 0; j < 4; ++j) {
          int l4 = (r * 8 + j) * 4;
          float4 v = rA[j];
          a += (double)v.x * sarr[l4 + 0];
          a += (double)v.y * sarr[l4 + 1];
          a += (double)v.z * sarr[l4 + 2];
          a += (double)v.w * sarr[l4 + 3];
        }
        if (r < 3) {
#pragma unroll
          for (int j = 0; j < 4; ++j) rA[j] = row[r * 8 + 8 + j];
        }
#pragma unroll
        for (int j = 0; j < 4; ++j) {
          int l4 = (r * 8 + 4 + j) * 4;
          float4 v = rB[j];
          a += (double)v.x * sarr[l4 + 0];
          a += (double)v.y * sarr[l4 + 1];
          a += (double)v.z * sarr[l4 + 2];
          a += (double)v.w * sarr[l4 + 3];
        }
      }
      gls[tid] = a;
    }
    __syncthreads();

    // ---- q2[h2] = sum_h gls[h]*pWqT[h][h2] + p_bq  (full f64; 32-deep batching) ----
    {
      const float* wcol = p.pWqT + tid;
      float wA[32], wB[32];
      double a = 0.0;
#pragma unroll
      for (int j = 0; j < 32; ++j) wA[j] = wcol[(size_t)j * HD];
#pragma unroll
      for (int pair = 0; pair < 8; ++pair) {
        const int hA = pair * 64;
#pragma unroll
        for (int j = 0; j < 32; ++j) wB[j] = wcol[(size_t)(hA + 32 + j) * HD];
#pragma unroll
        for (int j = 0; j < 32; ++j) a += gls[hA + j] * (double)wA[j];
        if (pair < 7) {
#pragma unroll
          for (int j = 0; j < 32; ++j) wA[j] = wcol[(size_t)(hA + 64 + j) * HD];
        }
#pragma unroll
        for (int j = 0; j < 32; ++j) a += gls[hA + 32 + j] * (double)wB[j];
      }
      qs[tid] = a + (double)p.pbq[tid];
      vs[tid] = p.pv[tid];
    }
    __syncthreads();

    // ---- pointer scores: same ping-pong on e_p (B0 already in flight) ----
    {
      double a0 = 0, a1 = 0, a2 = 0, a3 = 0;
#pragma unroll
      for (int j = 0; j < 8; ++j)
        B1[j] = *(const float4*)(epbase + (size_t)(8 + j) * (16 * LSEQ));
#pragma unroll
      for (int j = 0; j < 8; ++j) SCOMP(a0, a1, a2, a3, B0[j], j);
#pragma unroll
      for (int j = 0; j < 8; ++j)
        B0[j] = *(const float4*)(epbase + (size_t)(16 + j) * (16 * LSEQ));
#pragma unroll
      for (int j = 0; j < 8; ++j) SCOMP(a0, a1, a2, a3, B1[j], 8 + j);
#pragma unroll
      for (int j = 0; j < 8; ++j)
        B1[j] = *(const float4*)(epbase + (size_t)(24 + j) * (16 * LSEQ));
#pragma unroll
      for (int j = 0; j < 8; ++j) SCOMP(a0, a1, a2, a3, B0[j], 16 + j);
#pragma unroll
      for (int j = 0; j < 8; ++j) SCOMP(a0, a1, a2, a3, B1[j], 24 + j);
      part[hh][lg * 4 + 0] = a0;
      part[hh][lg * 4 + 1] = a1;
      part[hh][lg * 4 + 2] = a2;
      part[hh][lg * 4 + 3] = a3;
    }
    __syncthreads();

    double logit = 0.0, cand = 0.0;
    int idx = l;
    if (tid < 128) {
      double acc2 = 0.0;
#pragma unroll
      for (int o = 0; o < 16; ++o) acc2 += part[o][l];
      logit = msk ? -__builtin_inf() : 10.0 * tanh(acc2);     // C_EXPL = 10 (f64 libm)
      double mx = logit;
      for (int off = 32; off; off >>= 1) mx = fmax(mx, __shfl_xor(mx, off));
      if ((tid & 63) == 0) red[tid >> 6] = mx;
    }
    __syncthreads();
    if (tid < 128) {
      double mx = fmax(red[0], red[1]);
      double pe2 = msk ? 0.0 : exp(logit - mx);
      double sm = pe2;
      for (int off = 32; off; off >>= 1) sm += __shfl_xor(sm, off);
      if ((tid & 63) == 0) red[2 + (tid >> 6)] = sm;
    }
    __syncthreads();
    if (tid < 128) {
      double mx = fmax(red[0], red[1]);
      double pe2 = msk ? 0.0 : exp(logit - mx);
      p.out[(size_t)(t + 1) * BSZ * LSEQ + (size_t)b * LSEQ + l] = (float)(pe2 / (red[2] + red[3]));

      // gumbel, bit-exact vs jax.random.categorical
      uint32_t kA, kB;
      step_key(t, kA, kB);
      uint32_t bits = draw_bits(kA, kB, (uint32_t)(b * LSEQ + l));
      float f = __uint_as_float((bits >> 9) | 0x3f800000u) - 1.0f;
      const float TINY = 1.17549435e-38f;
      float uu = fmaxf(f * (1.0f - TINY) + TINY, TINY);
      float gmb = -logf(-logf(uu));
      cand = msk ? -__builtin_inf() : (logit + (double)gmb);

      for (int off = 32; off; off >>= 1) {
        double c2 = __shfl_xor(cand, off);
        int    i2 = __shfl_xor(idx, off);
        if (c2 > cand || (c2 == cand && i2 < idx)) { cand = c2; idx = i2; }
      }
      if ((tid & 63) == 0) { wv[tid >> 6] = cand; wi[tid >> 6] = idx; }
    }
    __syncthreads();
    if (tid == 0) {
      double c2 = wv[1]; int i2 = wi[1];
      if (c2 > cand || (c2 == cand && i2 < idx)) { cand = c2; idx = i2; }
      selidx = idx;
      p.out[SEL_OFF + (size_t)(t + 1) * BSZ + b] = (float)idx;
      p.mask[(size_t)b * LSEQ + idx] = 1;
    }
    __syncthreads();
    {
      int sidx = selidx;
      p.decb[(size_t)b * HD + tid] = p.emb[((size_t)sidx * BSZ + b) * HD + tid];
    }
    __threadfence();
    gridg.sync();
  }

  // ---- tail: hy / cy (final state is in hf1 / cb1 after t=126) ----
  {
    int i = bid * 512 + tid;
    p.out[HY_OFF + i] = p.hf1[i];
    p.out[CY_OFF + i] = (float)p.cb1[i];
  }
}

// ---------------- init ----------------
__global__ __launch_bounds__(256)
void init_kernel(const float* __restrict__ dec0, const float* __restrict__ h0,
                 const float* __restrict__ c0, float* __restrict__ dec_in,
                 float* __restrict__ hf, double* __restrict__ c,
                 unsigned char* __restrict__ mask, float* __restrict__ out)
{
  int i = blockIdx.x * blockDim.x + threadIdx.x;
  if (i < BSZ * HD) { hf[i] = h0[i]; c[i] = (double)c0[i]; dec_in[i] = dec0[i]; }
  if (i < BSZ * LSEQ) {
    mask[i] = ((i & (LSEQ - 1)) == 0) ? 1 : 0;
    out[i] = ((i & (LSEQ - 1)) == 0) ? 1.0f : 0.0f;
  }
  if (i < BSZ) out[SEL_OFF + i] = 0.0f;
}

// ---------------- host ----------------
extern "C" void kernel_launch(void* const* d_in, const int* in_sizes, int n_in,
                              void* d_out, int out_size, void* d_ws, size_t ws_size,
                              hipStream_t stream)
{
  (void)in_sizes; (void)n_in; (void)out_size; (void)ws_size;
  const float* dec0  = (const float*)d_in[0];
  const float* emb   = (const float*)d_in[1];
  const float* h0    = (const float*)d_in[2];
  const float* c0    = (const float*)d_in[3];
  const float* ctx   = (const float*)d_in[4];
  const float* Wi    = (const float*)d_in[5];
  const float* bi    = (const float*)d_in[6];
  const float* Wh    = (const float*)d_in[7];
  const float* bh    = (const float*)d_in[8];
  const float* gWq   = (const float*)d_in[9];
  const float* gbq   = (const float*)d_in[10];
  const float* gWref = (const float*)d_in[11];
  const float* gbref = (const float*)d_in[12];
  const float* gv    = (const float*)d_in[13];
  const float* pWq   = (const float*)d_in[14];
  const float* pbq   = (const float*)d_in[15];
  const float* pWref = (const float*)d_in[16];
  const float* pbref = (const float*)d_in[17];
  const float* pv    = (const float*)d_in[18];
  float* out = (float*)d_out;

  char* ws = (char*)d_ws;
  size_t off = 0;
  auto take = [&](size_t bytes) -> char* {
    char* p = ws + off;
    off += (bytes + 255) & ~(size_t)255;
    return p;
  };
  float*  e_g   = (float*) take((size_t)BSZ * LSEQ * HD * 4);   // [b][h][l]
  float*  e_p   = (float*) take((size_t)BSZ * LSEQ * HD * 4);   // [b][h][l]
  float*  g0f   = (float*) take((size_t)BSZ * G4 * 4);          // dec@Wi^T partial (f32)
  float*  g1f   = (float*) take((size_t)BSZ * G4 * 4);          // h@Wh^T partial (f32)
  double* cb0   = (double*)take((size_t)BSZ * HD * 8);
  double* cb1   = (double*)take((size_t)BSZ * HD * 8);
  float*  hf0   = (float*) take((size_t)BSZ * HD * 4);
  float*  hf1   = (float*) take((size_t)BSZ * HD * 4);
  float*  WqT   = (float*) take((size_t)HD * HD * 4);           // gWq^T
  float*  pWqT  = (float*) take((size_t)HD * HD * 4);           // pWq^T
  float*  decb  = (float*) take((size_t)BSZ * HD * 4);
  unsigned char* mask = (unsigned char*)take((size_t)BSZ * LSEQ);

  init_kernel<<<512, 256, 0, stream>>>(dec0, h0, c0, decb, hf0, cb0, mask, out);
  transpose512<<<dim3(16, 16), 256, 0, stream>>>(gWq, WqT);
  transpose512<<<dim3(16, 16), 256, 0, stream>>>(pWq, pWqT);

  // e_g / e_p -> [b][h][l] (mode 3)
  gemm32<8><<<dim3(BSZ * LSEQ / 64, HD / 64), 512, 0, stream>>>(
      ctx, HD, gWref, HD, gbref, e_g, HD, HD, 3);
  gemm32<8><<<dim3(BSZ * LSEQ / 64, HD / 64), 512, 0, stream>>>(
      ctx, HD, pWref, HD, pbref, e_p, HD, HD, 3);

  DecParams hp;
  hp.Wi = Wi; hp.Wh = Wh; hp.bi = bi; hp.bh = bh;
  hp.WqT = WqT; hp.gbq = gbq; hp.pWqT = pWqT; hp.pbq = pbq;
  hp.e_g = e_g; hp.e_p = e_p; hp.gv = gv; hp.pv = pv;
  hp.emb = emb;
  hp.g0f = g0f; hp.g1f = g1f;
  hp.hf0 = hf0; hp.hf1 = hf1;
  hp.cb0 = cb0; hp.cb1 = cb1;
  hp.decb = decb; hp.mask = mask; hp.out = out;

  void* args[] = { &hp };
  hipLaunchCooperativeKernel((void*)persistent_kernel, dim3(BSZ), dim3(512),
                             args, 0, stream);
}

// Round 14
// 13010.257 us; speedup vs baseline: 9.5429x; 9.5429x over previous
//
#include <hip/hip_runtime.h>
#include <stdint.h>

#ifndef THREEFRY_PARTITIONABLE
#define THREEFRY_PARTITIONABLE 1
#endif

#define LSEQ 128
#define BSZ  256
#define HD   512
#define G4   2048   // 4*HD

#define SEL_OFF  ((size_t)LSEQ * BSZ * LSEQ)            // 4194304
#define HY_OFF   (SEL_OFF + (size_t)LSEQ * BSZ)         // 4227072
#define CY_OFF   (HY_OFF + (size_t)BSZ * HD)            // 4358144

// ---------------- Threefry-2x32 (bit-exact vs JAX) ----------------
__device__ __forceinline__ uint32_t rotl_(uint32_t v, int r) { return (v << r) | (v >> (32 - r)); }

__device__ __forceinline__ void tf2x32(uint32_t k0, uint32_t k1,
                                       uint32_t x0, uint32_t x1,
                                       uint32_t &o0, uint32_t &o1)
{
  uint32_t k2 = k0 ^ k1 ^ 0x1BD11BDAu;
  x0 += k0; x1 += k1;
#define TFR(r) { x0 += x1; x1 = rotl_(x1,(r)); x1 ^= x0; }
  TFR(13) TFR(15) TFR(26) TFR(6)
  x0 += k1; x1 += k2 + 1u;
  TFR(17) TFR(29) TFR(16) TFR(24)
  x0 += k2; x1 += k0 + 2u;
  TFR(13) TFR(15) TFR(26) TFR(6)
  x0 += k0; x1 += k1 + 3u;
  TFR(17) TFR(29) TFR(16) TFR(24)
  x0 += k1; x1 += k2 + 4u;
  TFR(13) TFR(15) TFR(26) TFR(6)
  x0 += k2; x1 += k0 + 5u;
#undef TFR
  o0 = x0; o1 = x1;
}

__device__ __forceinline__ void step_key(int t, uint32_t &kA, uint32_t &kB)
{
#if THREEFRY_PARTITIONABLE
  uint32_t o0, o1;
  tf2x32(0u, 1u, 0u, (uint32_t)t, o0, o1);
  kA = o0; kB = o1;
#else
  uint32_t o0, o1;
  uint32_t j = 2u * (uint32_t)t;
  if (j < 127u) { tf2x32(0u, 1u, j, 127u + j, o0, o1); kA = o0; }
  else          { tf2x32(0u, 1u, j - 127u, j, o0, o1); kA = o1; }
  j = 2u * (uint32_t)t + 1u;
  if (j < 127u) { tf2x32(0u, 1u, j, 127u + j, o0, o1); kB = o0; }
  else          { tf2x32(0u, 1u, j - 127u, j, o0, o1); kB = o1; }
#endif
}

__device__ __forceinline__ uint32_t draw_bits(uint32_t kA, uint32_t kB, uint32_t n)
{
  uint32_t y0, y1;
#if THREEFRY_PARTITIONABLE
  tf2x32(kA, kB, 0u, n, y0, y1);
  return y0 ^ y1;
#else
  uint32_t i0 = (n < 16384u) ? n : n - 16384u;
  tf2x32(kA, kB, i0, i0 + 16384u, y0, y1);
  return (n < 16384u) ? y0 : y1;
#endif
}

// ---------------- fast f32 tanh (branch-free, ~1e-7 abs) ----------------
__device__ __forceinline__ float tanh_f(float xf)
{
  float ax = fabsf(xf);
  float z  = fminf(ax * 2.8853900817779268f, 50.0f);  // 2*log2(e), clamp
  float e  = __builtin_amdgcn_exp2f(z);
  float d  = e + 1.0f;
  float r0 = __builtin_amdgcn_rcpf(d);
  float r  = fmaf(fmaf(-d, r0, 1.0f), r0, r0);        // Newton: r ~= 1/d
  return copysignf(fmaf(-2.0f, r, 1.0f), xf);         // tanh(|x|) = 1 - 2/(e+1)
}

// ---------------- f32-input GEMM, chunked-f64 accumulate, 512 threads ----------------
// (R11 version: single-buffered LDS, register prefetch of next tile)
template<int CHUNK>
__global__ __launch_bounds__(512)
void gemm32(const float* __restrict__ A0, const float* __restrict__ A1, int lda,
            const float* __restrict__ B0, const float* __restrict__ B1, int ldb,
            const float* __restrict__ bias,
            double* __restrict__ Cd0, double* __restrict__ Cd1,
            float* __restrict__ Cf0, float* __restrict__ Cf1,
            int N, int K, int out_mode)
{
  constexpr int BM = 64;
  constexpr int BN = 64;
  constexpr int BK = 32;
  __shared__ float As[BK][BM];
  __shared__ float Bs[BK][BN];
  const int tid = threadIdx.x;
  const int tx = tid & 31, ty = tid >> 5;   // 32 cols-of-2, 16 rows-of-4
  const int z = blockIdx.z;
  const float* A = z ? A1 : A0;
  const float* B = z ? B1 : B0;
  const int m0 = blockIdx.x * BM;
  const int n0 = blockIdx.y * BN;

  const int r_ = tid >> 3, kq = (tid & 7) * 4;

  double acc[4][2];
  float  c32[4][2];
#pragma unroll
  for (int i = 0; i < 4; ++i)
#pragma unroll
    for (int j = 0; j < 2; ++j) { acc[i][j] = 0.0; c32[i][j] = 0.0f; }

  const float* bp0 = B + (size_t)(n0 + r_) * ldb + kq;
  float4 w0 = *(const float4*)bp0;
  const float* ap0 = A + (size_t)(m0 + r_) * lda + kq;
  float4 u0 = *(const float4*)ap0;

  for (int k0 = 0; k0 < K; k0 += BK) {
    __syncthreads();
    Bs[kq + 0][r_] = w0.x; Bs[kq + 1][r_] = w0.y;
    Bs[kq + 2][r_] = w0.z; Bs[kq + 3][r_] = w0.w;
    As[kq + 0][r_] = u0.x; As[kq + 1][r_] = u0.y;
    As[kq + 2][r_] = u0.z; As[kq + 3][r_] = u0.w;
    __syncthreads();

    float4 nw0 = w0, nu0 = u0;
    if (k0 + BK < K) {
      nw0 = *(const float4*)(B + (size_t)(n0 + r_) * ldb + (k0 + BK) + kq);
      nu0 = *(const float4*)(A + (size_t)(m0 + r_) * lda + (k0 + BK) + kq);
    }

#pragma unroll
    for (int kk = 0; kk < BK; ++kk) {
      float4 av = *(const float4*)&As[kk][4 * ty];
      float2 bv = *(const float2*)&Bs[kk][2 * tx];
      float a[4] = { av.x, av.y, av.z, av.w };
#pragma unroll
      for (int i = 0; i < 4; ++i) {
        c32[i][0] = fmaf(a[i], bv.x, c32[i][0]);
        c32[i][1] = fmaf(a[i], bv.y, c32[i][1]);
      }
      if ((kk & (CHUNK - 1)) == (CHUNK - 1)) {
#pragma unroll
        for (int i = 0; i < 4; ++i)
#pragma unroll
          for (int j = 0; j < 2; ++j) { acc[i][j] += (double)c32[i][j]; c32[i][j] = 0.0f; }
      }
    }
    w0 = nw0; u0 = nu0;
  }

#pragma unroll
  for (int i = 0; i < 4; ++i) {
    int m = m0 + 4 * ty + i;
#pragma unroll
    for (int j = 0; j < 2; ++j) {
      int n = n0 + 2 * tx + j;
      double v = acc[i][j] + (bias ? (double)bias[n] : 0.0);
      if (out_mode == 0) {
        double* Cd = z ? Cd1 : Cd0;
        Cd[(size_t)m * N + n] = v;
      } else if (out_mode == 1) {
        Cf0[(((size_t)(m & 255)) * LSEQ + (m >> 8)) * HD + n] = (float)v;
      } else if (out_mode == 2) {
        Cf0[(size_t)m * N + n] = (float)v;
      } else if (out_mode == 3) {
        Cf0[(((size_t)(m & 255)) * HD + n) * LSEQ + (m >> 8)] = (float)v;
      } else {
        float* Cf = z ? Cf1 : Cf0;
        Cf[(size_t)m * N + n] = (float)v;
      }
    }
  }
}

// ---------------- 512x512 transpose ----------------
__global__ __launch_bounds__(256)
void transpose512(const float* __restrict__ W, float* __restrict__ WT)
{
  __shared__ float tile[32][33];
  int bx = blockIdx.x * 32, by = blockIdx.y * 32;
  int x = threadIdx.x & 31, y = threadIdx.x >> 5;   // 32 x 8
#pragma unroll
  for (int j = 0; j < 32; j += 8)
    tile[y + j][x] = W[(size_t)(by + y + j) * HD + bx + x];
  __syncthreads();
#pragma unroll
  for (int j = 0; j < 32; j += 8)
    WT[(size_t)(bx + y + j) * HD + by + x] = tile[x][y + j];
}

// score-phase per-element compute: pure-f32 tanh, f64 accumulate
#define SCOMP(A0_, A1_, A2_, A3_, V4, IT)                         \
  {                                                               \
    const int h_ = (IT) * 16 + hh;                                \
    const float  xq_ = (float)qs[h_];                             \
    const double vv_ = (double)vs[h_];                            \
    A0_ += vv_ * (double)tanh_f(xq_ + (V4).x);                    \
    A1_ += vv_ * (double)tanh_f(xq_ + (V4).y);                    \
    A2_ += vv_ * (double)tanh_f(xq_ + (V4).z);                    \
    A3_ += vv_ * (double)tanh_f(xq_ + (V4).w);                    \
  }

// ---------------- fused step, 512 threads (R11 = best verified) ----------------
__global__ __launch_bounds__(512)
void step_fused(const float* __restrict__ g0, const float* __restrict__ g1,
                const float* __restrict__ bi, const float* __restrict__ bh,
                const double* __restrict__ c_in, double* __restrict__ c_out,
                float* __restrict__ h_out,
                const float* __restrict__ WqT, const float* __restrict__ g_bq,
                const float* __restrict__ e_g,
                const float* __restrict__ pWqT, const float* __restrict__ p_bq,
                const float* __restrict__ e_p,
                const float* __restrict__ g_v, const float* __restrict__ p_v,
                unsigned char* __restrict__ mask,
                const float* __restrict__ emb, float* __restrict__ dec_in,
                float* __restrict__ out, int t)
{
  const int b   = blockIdx.x;
  const int tid = threadIdx.x;
  const int l   = tid & 127;
  const int lg  = tid & 31;          // l-group: owns l = 4*lg .. 4*lg+3
  const int hh  = tid >> 5;          // 0..15   (h residue class)
  __shared__ float  hs[HD];
  __shared__ double qs[HD];          // q1, then q2
  __shared__ float  vs[HD];          // g_v, then p_v
  __shared__ double part[16][LSEQ];  // per-hh partials
  __shared__ double gls[HD];         // g_l (f64)
  __shared__ double sarr[LSEQ];
  __shared__ double red[4];
  __shared__ double wv[2];
  __shared__ int    wi[2];
  __shared__ int    selidx;

  const float* egbase = e_g + (size_t)b * (HD * LSEQ) + hh * LSEQ + lg * 4;
  const float* epbase = e_p + (size_t)b * (HD * LSEQ) + hh * LSEQ + lg * 4;

  // early prefetch: glimpse batch 0 (latency hides under LSTM)
  float4 B0[8], B1[8];
#pragma unroll
  for (int j = 0; j < 8; ++j)
    B0[j] = *(const float4*)(egbase + (size_t)j * (16 * LSEQ));

  // ---- LSTM pointwise, u = tid (identical f64 math) ----
  {
    const int u = tid;
    const size_t base = (size_t)b * G4;
    double gi = (double)g0[base + u]        + (double)g1[base + u]        + (double)bi[u]        + (double)bh[u];
    double gf = (double)g0[base + u + 512]  + (double)g1[base + u + 512]  + (double)bi[u + 512]  + (double)bh[u + 512];
    double gg = (double)g0[base + u + 1024] + (double)g1[base + u + 1024] + (double)bi[u + 1024] + (double)bh[u + 1024];
    double go = (double)g0[base + u + 1536] + (double)g1[base + u + 1536] + (double)bi[u + 1536] + (double)bh[u + 1536];
    double si = 1.0 / (1.0 + exp(-gi));
    double sf = 1.0 / (1.0 + exp(-gf));
    double so = 1.0 / (1.0 + exp(-go));
    double cy = sf * c_in[(size_t)b * HD + u] + si * tanh(gg);
    double hy = so * tanh(cy);
    c_out[(size_t)b * HD + u] = cy;
    float hyf = (float)hy;
    h_out[(size_t)b * HD + u] = hyf;
    hs[u] = hyf;
  }
  __syncthreads();

  // ---- q1[h] = sum_k hs[k]*WqT[k][h], chunks of 8 -> f64, 32-deep batching ----
  {
    const int h = tid;
    const float* wcol = WqT + h;
    float wA[32], wB[32];
    double a = 0.0;
#pragma unroll
    for (int j = 0; j < 32; ++j) wA[j] = wcol[(size_t)j * HD];
#pragma unroll
    for (int pair = 0; pair < 8; ++pair) {
      const int kA = pair * 64;
#pragma unroll
      for (int j = 0; j < 32; ++j) wB[j] = wcol[(size_t)(kA + 32 + j) * HD];
#pragma unroll
      for (int c = 0; c < 4; ++c) {
        float c32 = 0.0f;
#pragma unroll
        for (int j = 0; j < 8; ++j)
          c32 = fmaf(hs[kA + c * 8 + j], wA[c * 8 + j], c32);
        a += (double)c32;
      }
      if (pair < 7) {
#pragma unroll
        for (int j = 0; j < 32; ++j) wA[j] = wcol[(size_t)(kA + 64 + j) * HD];
      }
#pragma unroll
      for (int c = 0; c < 4; ++c) {
        float c32 = 0.0f;
#pragma unroll
        for (int j = 0; j < 8; ++j)
          c32 = fmaf(hs[kA + 32 + c * 8 + j], wB[c * 8 + j], c32);
        a += (double)c32;
      }
    }
    qs[tid] = a + (double)g_bq[tid];
    vs[tid] = g_v[tid];
  }
  __syncthreads();

  // ---- glimpse scores: ping-pong 8-batches ----
  {
    double a0 = 0, a1 = 0, a2 = 0, a3 = 0;
#pragma unroll
    for (int j = 0; j < 8; ++j)
      B1[j] = *(const float4*)(egbase + (size_t)(8 + j) * (16 * LSEQ));
#pragma unroll
    for (int j = 0; j < 8; ++j) SCOMP(a0, a1, a2, a3, B0[j], j);
#pragma unroll
    for (int j = 0; j < 8; ++j)
      B0[j] = *(const float4*)(egbase + (size_t)(16 + j) * (16 * LSEQ));
#pragma unroll
    for (int j = 0; j < 8; ++j) SCOMP(a0, a1, a2, a3, B1[j], 8 + j);
#pragma unroll
    for (int j = 0; j < 8; ++j)
      B1[j] = *(const float4*)(egbase + (size_t)(24 + j) * (16 * LSEQ));
#pragma unroll
    for (int j = 0; j < 8; ++j) SCOMP(a0, a1, a2, a3, B0[j], 16 + j);
#pragma unroll
    for (int j = 0; j < 8; ++j) SCOMP(a0, a1, a2, a3, B1[j], 24 + j);
    part[hh][lg * 4 + 0] = a0;
    part[hh][lg * 4 + 1] = a1;
    part[hh][lg * 4 + 2] = a2;
    part[hh][lg * 4 + 3] = a3;
  }
  __syncthreads();

  bool   msk = false;
  double u = 0.0, pe = 0.0;
  if (tid < 128) {
    msk = mask[(size_t)b * LSEQ + l] != 0;
    u = 0.0;
#pragma unroll
    for (int o = 0; o < 16; ++o) u += part[o][l];
    if (msk) u = -__builtin_inf();
    double mx = u;
    for (int off = 32; off; off >>= 1) mx = fmax(mx, __shfl_xor(mx, off));
    if ((tid & 63) == 0) red[tid >> 6] = mx;
  }
  __syncthreads();
  if (tid < 128) {
    double mx = fmax(red[0], red[1]);
    pe = msk ? 0.0 : exp(u - mx);
    double sm = pe;
    for (int off = 32; off; off >>= 1) sm += __shfl_xor(sm, off);
    if ((tid & 63) == 0) red[2 + (tid >> 6)] = sm;
  }
  __syncthreads();
  if (tid < 128) sarr[l] = pe / (red[2] + red[3]);
  __syncthreads();

  // ---- g_l[h] = sum_l e_g[b][h][l]*s[l]  (contiguous rows, f64 acc) ----
  {
    // prefetch pointer batch 0 (latency hides under g_l + q2)
#pragma unroll
    for (int j = 0; j < 8; ++j)
      B0[j] = *(const float4*)(epbase + (size_t)j * (16 * LSEQ));

    const float4* row = (const float4*)(e_g + ((size_t)b * HD + tid) * LSEQ);
    float4 rA[4], rB[4];
    double a = 0.0;
#pragma unroll
    for (int j = 0; j < 4; ++j) rA[j] = row[j];
#pragma unroll
    for (int r = 0; r < 4; ++r) {
#pragma unroll
      for (int j = 0; j < 4; ++j) rB[j] = row[r * 8 + 4 + j];
#pragma unroll
      for (int j = 0; j < 4; ++j) {
        int l4 = (r * 8 + j) * 4;
        float4 v = rA[j];
        a += (double)v.x * sarr[l4 + 0];
        a += (double)v.y * sarr[l4 + 1];
        a += (double)v.z * sarr[l4 + 2];
        a += (double)v.w * sarr[l4 + 3];
      }
      if (r < 3) {
#pragma unroll
        for (int j = 0; j < 4; ++j) rA[j] = row[r * 8 + 8 + j];
      }
#pragma unroll
      for (int j = 0; j < 4; ++j) {
        int l4 = (r * 8 + 4 + j) * 4;
        float4 v = rB[j];
        a += (double)v.x * sarr[l4 + 0];
        a += (double)v.y * sarr[l4 + 1];
        a += (double)v.z * sarr[l4 + 2];
        a += (double)v.w * sarr[l4 + 3];
      }
    }
    gls[tid] = a;
  }
  __syncthreads();

  // ---- q2[h2] = sum_h gls[h]*pWqT[h][h2] + p_bq  (full f64; 32-deep batching) ----
  {
    const float* wcol = pWqT + tid;
    float wA[32], wB[32];
    double a = 0.0;
#pragma unroll
    for (int j = 0; j < 32; ++j) wA[j] = wcol[(size_t)j * HD];
#pragma unroll
    for (int pair = 0; pair < 8; ++pair) {
      const int hA = pair * 64;
#pragma unroll
      for (int j = 0; j < 32; ++j) wB[j] = wcol[(size_t)(hA + 32 + j) * HD];
#pragma unroll
      for (int j = 0; j < 32; ++j) a += gls[hA + j] * (double)wA[j];
      if (pair < 7) {
#pragma unroll
        for (int j = 0; j < 32; ++j) wA[j] = wcol[(size_t)(hA + 64 + j) * HD];
      }
#pragma unroll
      for (int j = 0; j < 32; ++j) a += gls[hA + 32 + j] * (double)wB[j];
    }
    qs[tid] = a + (double)p_bq[tid];
    vs[tid] = p_v[tid];
  }
  __syncthreads();

  // ---- pointer scores: same ping-pong on e_p (B0 already in flight) ----
  {
    double a0 = 0, a1 = 0, a2 = 0, a3 = 0;
#pragma unroll
    for (int j = 0; j < 8; ++j)
      B1[j] = *(const float4*)(epbase + (size_t)(8 + j) * (16 * LSEQ));
#pragma unroll
    for (int j = 0; j < 8; ++j) SCOMP(a0, a1, a2, a3, B0[j], j);
#pragma unroll
    for (int j = 0; j < 8; ++j)
      B0[j] = *(const float4*)(epbase + (size_t)(16 + j) * (16 * LSEQ));
#pragma unroll
    for (int j = 0; j < 8; ++j) SCOMP(a0, a1, a2, a3, B1[j], 8 + j);
#pragma unroll
    for (int j = 0; j < 8; ++j)
      B1[j] = *(const float4*)(epbase + (size_t)(24 + j) * (16 * LSEQ));
#pragma unroll
    for (int j = 0; j < 8; ++j) SCOMP(a0, a1, a2, a3, B0[j], 16 + j);
#pragma unroll
    for (int j = 0; j < 8; ++j) SCOMP(a0, a1, a2, a3, B1[j], 24 + j);
    part[hh][lg * 4 + 0] = a0;
    part[hh][lg * 4 + 1] = a1;
    part[hh][lg * 4 + 2] = a2;
    part[hh][lg * 4 + 3] = a3;
  }
  __syncthreads();

  double logit = 0.0, cand = 0.0;
  int idx = l;
  if (tid < 128) {
    double acc2 = 0.0;
#pragma unroll
    for (int o = 0; o < 16; ++o) acc2 += part[o][l];
    logit = msk ? -__builtin_inf() : 10.0 * tanh(acc2);     // C_EXPL = 10 (f64 libm)
    double mx = logit;
    for (int off = 32; off; off >>= 1) mx = fmax(mx, __shfl_xor(mx, off));
    if ((tid & 63) == 0) red[tid >> 6] = mx;
  }
  __syncthreads();
  if (tid < 128) {
    double mx = fmax(red[0], red[1]);
    double pe2 = msk ? 0.0 : exp(logit - mx);
    double sm = pe2;
    for (int off = 32; off; off >>= 1) sm += __shfl_xor(sm, off);
    if ((tid & 63) == 0) red[2 + (tid >> 6)] = sm;
  }
  __syncthreads();
  if (tid < 128) {
    double mx = fmax(red[0], red[1]);
    double pe2 = msk ? 0.0 : exp(logit - mx);
    out[(size_t)(t + 1) * BSZ * LSEQ + (size_t)b * LSEQ + l] = (float)(pe2 / (red[2] + red[3]));

    // gumbel, bit-exact vs jax.random.categorical
    uint32_t kA, kB;
    step_key(t, kA, kB);
    uint32_t bits = draw_bits(kA, kB, (uint32_t)(b * LSEQ + l));
    float f = __uint_as_float((bits >> 9) | 0x3f800000u) - 1.0f;
    const float TINY = 1.17549435e-38f;
    float uu = fmaxf(f * (1.0f - TINY) + TINY, TINY);
    float gmb = -logf(-logf(uu));
    cand = msk ? -__builtin_inf() : (logit + (double)gmb);

    for (int off = 32; off; off >>= 1) {
      double c2 = __shfl_xor(cand, off);
      int    i2 = __shfl_xor(idx, off);
      if (c2 > cand || (c2 == cand && i2 < idx)) { cand = c2; idx = i2; }
    }
    if ((tid & 63) == 0) { wv[tid >> 6] = cand; wi[tid >> 6] = idx; }
  }
  __syncthreads();
  if (tid == 0) {
    double c2 = wv[1]; int i2 = wi[1];
    if (c2 > cand || (c2 == cand && i2 < idx)) { cand = c2; idx = i2; }
    selidx = idx;
    out[SEL_OFF + (size_t)(t + 1) * BSZ + b] = (float)idx;
    mask[(size_t)b * LSEQ + idx] = 1;
  }
  __syncthreads();
  {
    int sidx = selidx;
    dec_in[(size_t)b * HD + tid] = emb[((size_t)sidx * BSZ + b) * HD + tid];
  }
}

// ---------------- init / finalize ----------------
__global__ __launch_bounds__(256)
void init_kernel(const float* __restrict__ dec0, const float* __restrict__ h0,
                 const float* __restrict__ c0, float* __restrict__ dec_in,
                 float* __restrict__ hf, double* __restrict__ c,
                 unsigned char* __restrict__ mask, float* __restrict__ out)
{
  int i = blockIdx.x * blockDim.x + threadIdx.x;
  if (i < BSZ * HD) { hf[i] = h0[i]; c[i] = (double)c0[i]; dec_in[i] = dec0[i]; }
  if (i < BSZ * LSEQ) {
    mask[i] = ((i & (LSEQ - 1)) == 0) ? 1 : 0;
    out[i] = ((i & (LSEQ - 1)) == 0) ? 1.0f : 0.0f;
  }
  if (i < BSZ) out[SEL_OFF + i] = 0.0f;
}

__global__ __launch_bounds__(256)
void finalize(const float* __restrict__ hf, const double* __restrict__ c,
              float* __restrict__ out)
{
  int i = blockIdx.x * blockDim.x + threadIdx.x;
  if (i < BSZ * HD) {
    out[HY_OFF + i] = hf[i];
    out[CY_OFF + i] = (float)c[i];
  }
}

// ---------------- host ----------------
extern "C" void kernel_launch(void* const* d_in, const int* in_sizes, int n_in,
                              void* d_out, int out_size, void* d_ws, size_t ws_size,
                              hipStream_t stream)
{
  (void)in_sizes; (void)n_in; (void)out_size; (void)ws_size;
  const float* dec0  = (const float*)d_in[0];
  const float* emb   = (const float*)d_in[1];
  const float* h0    = (const float*)d_in[2];
  const float* c0    = (const float*)d_in[3];
  const float* ctx   = (const float*)d_in[4];
  const float* Wi    = (const float*)d_in[5];
  const float* bi    = (const float*)d_in[6];
  const float* Wh    = (const float*)d_in[7];
  const float* bh    = (const float*)d_in[8];
  const float* gWq   = (const float*)d_in[9];
  const float* gbq   = (const float*)d_in[10];
  const float* gWref = (const float*)d_in[11];
  const float* gbref = (const float*)d_in[12];
  const float* gv    = (const float*)d_in[13];
  const float* pWq   = (const float*)d_in[14];
  const float* pbq   = (const float*)d_in[15];
  const float* pWref = (const float*)d_in[16];
  const float* pbref = (const float*)d_in[17];
  const float* pv    = (const float*)d_in[18];
  float* out = (float*)d_out;

  char* ws = (char*)d_ws;
  size_t off = 0;
  auto take = [&](size_t bytes) -> char* {
    char* p = ws + off;
    off += (bytes + 255) & ~(size_t)255;
    return p;
  };
  float*  e_g   = (float*) take((size_t)BSZ * LSEQ * HD * 4);   // [b][h][l]
  float*  e_p   = (float*) take((size_t)BSZ * LSEQ * HD * 4);   // [b][h][l]
  float*  g0f   = (float*) take((size_t)BSZ * G4 * 4);          // dec@Wi^T partial (f32)
  float*  g1f   = (float*) take((size_t)BSZ * G4 * 4);          // h@Wh^T partial (f32)
  double* cb0   = (double*)take((size_t)BSZ * HD * 8);
  double* cb1   = (double*)take((size_t)BSZ * HD * 8);
  float*  hf0   = (float*) take((size_t)BSZ * HD * 4);
  float*  hf1   = (float*) take((size_t)BSZ * HD * 4);
  float*  WqT   = (float*) take((size_t)HD * HD * 4);           // gWq^T
  float*  pWqT  = (float*) take((size_t)HD * HD * 4);           // pWq^T
  float*  decb  = (float*) take((size_t)BSZ * HD * 4);
  unsigned char* mask = (unsigned char*)take((size_t)BSZ * LSEQ);

  init_kernel<<<512, 256, 0, stream>>>(dec0, h0, c0, decb, hf0, cb0, mask, out);
  transpose512<<<dim3(16, 16), 256, 0, stream>>>(gWq, WqT);
  transpose512<<<dim3(16, 16), 256, 0, stream>>>(pWq, pWqT);

  // e_g / e_p -> [b][h][l] (mode 3)
  gemm32<8><<<dim3(BSZ * LSEQ / 64, HD / 64, 1), 512, 0, stream>>>(
      ctx, nullptr, HD, gWref, nullptr, HD, gbref,
      nullptr, nullptr, e_g, nullptr, HD, HD, 3);
  gemm32<8><<<dim3(BSZ * LSEQ / 64, HD / 64, 1), 512, 0, stream>>>(
      ctx, nullptr, HD, pWref, nullptr, HD, pbref,
      nullptr, nullptr, e_p, nullptr, HD, HD, 3);

  double* cb[2] = { cb0, cb1 };
  float*  hf[2] = { hf0, hf1 };
  for (int t = 0; t < LSEQ - 1; ++t) {
    int rs = t & 1, wsl = rs ^ 1;
    // K1: gates partials (f32 out): z=0: dec_in@Wi^T -> g0f ; z=1: h@Wh^T -> g1f
    gemm32<8><<<dim3(BSZ / 64, G4 / 64, 2), 512, 0, stream>>>(
        decb, hf[rs], HD, Wi, Wh, HD, nullptr,
        nullptr, nullptr, g0f, g1f, G4, HD, 4);
    // K2: LSTM + q1 + glimpse + g_l + q2(pWqT) + pointer + sample + gather
    step_fused<<<BSZ, 512, 0, stream>>>(g0f, g1f, bi, bh,
                                        cb[rs], cb[wsl], hf[wsl],
                                        WqT, gbq, e_g, pWqT, pbq, e_p, gv, pv,
                                        mask, emb, decb, out, t);
  }
  finalize<<<BSZ * HD / 256, 256, 0, stream>>>(hf[1], cb[1], out);
}